// Round 6
// baseline (116.799 us; speedup 1.0000x reference)
//
#include <hip/hip_runtime.h>
#include <stdint.h>

// Problem constants (fixed by the reference)
#define NB    32768   // batch
#define NS    16      // states per element
#define SS    32      // state size (K of stage 1)
#define ENCD  64      // encoder width
#define HIDD  128     // hidden width
#define OUTD  8       // output logits
#define BPW   16      // batches per WAVE (wave-independent design)
#define BT    64      // 4 waves x 16 batches per block
#define THREADS 256   // 4 waves

typedef _Float16 half8  __attribute__((ext_vector_type(8)));  // 8 f16 = 4 VGPRs
typedef __fp16   fp16x2 __attribute__((ext_vector_type(2)));  // cvt_pkrtz result type
typedef float    f32x4  __attribute__((ext_vector_type(4)));

#define MFMA(a, b, c) __builtin_amdgcn_mfma_f32_16x16x32_f16((a), (b), (c), 0, 0, 0)
// Wave-local LDS ordering: waves are lockstep (one instruction stream), so
// issue order is program order; lgkmcnt(0) guarantees completion. No
// __syncthreads anywhere in this kernel.
#define WAVE_LGKM0() asm volatile("s_waitcnt lgkmcnt(0)" ::: "memory")

// Split 8 floats into fp16 hi + lo: f = hi + lo + O(2^-20 |f|).
__device__ __forceinline__ void split8(const float* f, half8& hi, half8& lo) {
#pragma unroll
  for (int j = 0; j < 8; j += 2) {
    fp16x2 h  = __builtin_amdgcn_cvt_pkrtz(f[j], f[j + 1]);
    float  r0 = f[j]     - (float)h[0];
    float  r1 = f[j + 1] - (float)h[1];
    fp16x2 l2 = __builtin_amdgcn_cvt_pkrtz(r0, r1);
    hi[j] = (_Float16)(float)h[0];  hi[j + 1] = (_Float16)(float)h[1];
    lo[j] = (_Float16)(float)l2[0]; lo[j + 1] = (_Float16)(float)l2[1];
  }
}

// R5 post-mortem: block-cooperative structure is knob-exhausted at ~28 us;
// counters (r2/r4) show all pipes idle -> bulk-sync stalls, not a resource
// limit. This version: each WAVE owns 16 batches end-to-end. No barriers,
// no idle waves in stage 4, deep (depth-3) obs pipeline, per-batch cost
// identical to r0 by construction. Grid 512 -> occupancy is grid-limited
// (8 waves/CU), so (256,2) lets VGPR run to 256: spilling impossible.
__global__ __launch_bounds__(THREADS, 2)
void gnn_fused(const float* __restrict__ obs,
               const float* __restrict__ W_enc,
               const float* __restrict__ b_enc,
               const float* __restrict__ W_f,
               const float* __restrict__ b_f,
               const float* __restrict__ W_dec,
               const float* __restrict__ b_dec,
               float* __restrict__ out)
{
  // Per-wave scratch, REUSED: stage-2 writes f_in here, stage-3 reads it
  // fully into registers, then overwrites the same rows with hidn.
  // stride 132: rows 528 B (16B-aligned), row-to-row bank shift of 4.
  __shared__ __align__(16) float scr[4][BPW][132];   // 33.8 KiB/block

  const int tid  = threadIdx.x;
  const int w    = tid >> 6;     // wave 0..3
  const int l    = tid & 63;     // lane
  const int m15  = l & 15;
  const int quad = l >> 4;
  const int b0   = blockIdx.x * BT + w * BPW;   // this wave's first batch
  float (*S)[132] = scr[w];

  // ---- stage-1 B-fragments: W_enc[k][e] columns, hi/lo fp16, in regs
  half8 we_hi[4], we_lo[4];
  float benc[4];
#pragma unroll
  for (int nt = 0; nt < 4; ++nt) {
    float f[8];
#pragma unroll
    for (int j = 0; j < 8; ++j)
      f[j] = W_enc[(size_t)(quad * 8 + j) * ENCD + nt * 16 + m15];
    split8(f, we_hi[nt], we_lo[nt]);
    benc[nt] = b_enc[nt * 16 + m15];
  }

  // ================= stage 1 (enc MFMA) + stage 2 (masked mean-pool) =========
  // 16 batches per wave, depth-3 modulo-rotated obs staging (fully unrolled,
  // all slot indices static). 6 dwordx4 in flight at steady state.
  const float* bp = obs + (size_t)b0 * (NS * SS) + m15 * SS + quad * 8;
  float4 A0[3], A1[3];
#pragma unroll
  for (int i = 0; i < 3; ++i) {
    const float4* p = (const float4*)(bp + (size_t)i * (NS * SS));
    A0[i] = p[0]; A1[i] = p[1];
  }

#pragma unroll
  for (int i = 0; i < BPW; ++i) {
    const int sl = i % 3;                       // static after full unroll
    float f[8] = {A0[sl].x, A0[sl].y, A0[sl].z, A0[sl].w,
                  A1[sl].x, A1[sl].y, A1[sl].z, A1[sl].w};
    if (i < BPW - 3) {                          // refill consumed slot (i+3)
      const float4* p = (const float4*)(bp + (size_t)(i + 3) * (NS * SS));
      A0[sl] = p[0]; A1[sl] = p[1];
    }

    // flags: lanes 0..15 hold states[b][n][0]; run length via ballot+ctz
    unsigned long long bal = __ballot((l < 16) && (f[0] == 1.0f));
    int run = __builtin_ctzll(~(bal >> 1));     // consecutive valid neighbors
    float inv = 1.0f / fmaxf((float)run, 1.0f);

    half8 ahi, alo;
    split8(f, ahi, alo);

#pragma unroll
    for (int nt = 0; nt < 4; ++nt) {
      f32x4 acc = {0.f, 0.f, 0.f, 0.f};
      acc = MFMA(ahi, we_hi[nt], acc);
      acc = MFMA(alo, we_hi[nt], acc);
      acc = MFMA(ahi, we_lo[nt], acc);
      // D layout: lane holds enc[n = quad*4 + r][e = nt*16 + m15]
      float s = 0.f, e0 = 0.f;
#pragma unroll
      for (int r = 0; r < 4; ++r) {
        int n = quad * 4 + r;
        float v = fmaxf(acc[r] + benc[nt], 0.f);
        if (n == 0) e0 = v;                    // agent row
        if (n >= 1 && n <= run) s += v;        // valid neighbor
      }
      s += __shfl_xor(s, 16, 64);              // reduce across quads
      s += __shfl_xor(s, 32, 64);
      if (quad == 0) {
        S[i][nt * 16 + m15]      = e0;          // agent_enc
        S[i][64 + nt * 16 + m15] = s * inv;     // agg
      }
    }
  }
  WAVE_LGKM0();   // f_in writes visible to all lanes of this wave

  // ================= stage 3: hidden = relu(f_in @ W_f + b_f) ================
  // This wave's full 16-row M-tile x all 128 h-columns (8 N-tiles).
  half8 fa_hi[4], fa_lo[4];
#pragma unroll
  for (int ks = 0; ks < 4; ++ks) {
    const float4* p = (const float4*)&S[m15][ks * 32 + quad * 8];
    float4 a = p[0], b = p[1];
    float f[8] = {a.x, a.y, a.z, a.w, b.x, b.y, b.z, b.w};
    split8(f, fa_hi[ks], fa_lo[ks]);
  }
  WAVE_LGKM0();   // f_in fully read -> safe to overwrite S with hidn

#pragma unroll 2
  for (int tt = 0; tt < 8; ++tt) {
    const int h0 = tt * 16 + m15;               // output column
    f32x4 acc = {0.f, 0.f, 0.f, 0.f};
#pragma unroll
    for (int ks = 0; ks < 4; ++ks) {
      float f[8];
#pragma unroll
      for (int j = 0; j < 8; ++j)               // W_f chunk (L1/L2 resident)
        f[j] = W_f[(size_t)(ks * 32 + quad * 8 + j) * HIDD + h0];
      half8 bhi, blo;
      split8(f, bhi, blo);
      acc = MFMA(fa_hi[ks], bhi, acc);
      acc = MFMA(fa_lo[ks], bhi, acc);
      acc = MFMA(fa_hi[ks], blo, acc);
    }
    const float bfv = b_f[h0];
#pragma unroll
    for (int r = 0; r < 4; ++r)                 // D: row = batch, col = h0
      S[quad * 4 + r][h0] = fmaxf(acc[r] + bfv, 0.f);
  }
  WAVE_LGKM0();   // hidn writes complete before stage-4 reads

  // ================= stage 4: logits = hidden @ W_dec + b_dec ================
  // Every wave finishes its own 16 batches (no idle waves, no w==0 guard).
  {
    half8 ga_hi[4], ga_lo[4];
#pragma unroll
    for (int ks = 0; ks < 4; ++ks) {
      const float4* p = (const float4*)&S[m15][ks * 32 + quad * 8];
      float4 a = p[0], b = p[1];
      float f[8] = {a.x, a.y, a.z, a.w, b.x, b.y, b.z, b.w};
      split8(f, ga_hi[ks], ga_lo[ks]);
    }
    f32x4 acc = {0.f, 0.f, 0.f, 0.f};
#pragma unroll
    for (int ks = 0; ks < 4; ++ks) {
      float f[8];
#pragma unroll
      for (int j = 0; j < 8; ++j) {
        int k = ks * 32 + quad * 8 + j;
        f[j] = (m15 < OUTD) ? W_dec[(size_t)k * OUTD + m15] : 0.f;  // pad N 8->16
      }
      half8 bhi, blo;
      split8(f, bhi, blo);
      acc = MFMA(ga_hi[ks], bhi, acc);
      acc = MFMA(ga_lo[ks], bhi, acc);
      acc = MFMA(ga_hi[ks], blo, acc);
    }
    if (m15 < OUTD) {
      const float bd = b_dec[m15];
#pragma unroll
      for (int r = 0; r < 4; ++r) {
        const int m = quad * 4 + r;
        out[(size_t)(b0 + m) * OUTD + m15] = acc[r] + bd;
      }
    }
  }
}

extern "C" void kernel_launch(void* const* d_in, const int* in_sizes, int n_in,
                              void* d_out, int out_size, void* d_ws, size_t ws_size,
                              hipStream_t stream) {
  (void)in_sizes; (void)n_in; (void)d_ws; (void)ws_size; (void)out_size;
  const float* obs   = (const float*)d_in[0];
  const float* W_enc = (const float*)d_in[1];
  const float* b_enc = (const float*)d_in[2];
  const float* W_f   = (const float*)d_in[3];
  const float* b_f   = (const float*)d_in[4];
  const float* W_dec = (const float*)d_in[5];
  const float* b_dec = (const float*)d_in[6];
  float* out = (float*)d_out;

  dim3 grid(NB / BT);      // 512 blocks (2 per CU, all co-resident)
  dim3 block(THREADS);     // 4 waves, each fully independent
  gnn_fused<<<grid, block, 0, stream>>>(obs, W_enc, b_enc, W_f, b_f, W_dec, b_dec, out);
}

// Round 7
// 111.743 us; speedup vs baseline: 1.0452x; 1.0452x over previous
//
#include <hip/hip_runtime.h>
#include <stdint.h>

// Problem constants (fixed by the reference)
#define NB    32768   // batch
#define NS    16      // states per element
#define SS    32      // state size (K of stage 1)
#define ENCD  64      // encoder width
#define HIDD  128     // hidden width
#define OUTD  8       // output logits
#define BT    16      // batch elements per block
#define THREADS 256   // 4 waves

typedef _Float16 half8  __attribute__((ext_vector_type(8)));  // 8 f16 = 4 VGPRs
typedef __fp16   fp16x2 __attribute__((ext_vector_type(2)));  // cvt_pkrtz result type
typedef float    f32x4  __attribute__((ext_vector_type(4)));

#define MFMA(a, b, c) __builtin_amdgcn_mfma_f32_16x16x32_f16((a), (b), (c), 0, 0, 0)

// Split 8 floats into fp16 hi + lo: f = hi + lo + O(2^-20 |f|).
// v_cvt_pkrtz packs 2 floats -> 2 f16 in ONE VALU op (RTZ; lo captures the error).
__device__ __forceinline__ void split8(const float* f, half8& hi, half8& lo) {
#pragma unroll
  for (int j = 0; j < 8; j += 2) {
    fp16x2 h  = __builtin_amdgcn_cvt_pkrtz(f[j], f[j + 1]);
    float  r0 = f[j]     - (float)h[0];
    float  r1 = f[j + 1] - (float)h[1];
    fp16x2 l2 = __builtin_amdgcn_cvt_pkrtz(r0, r1);
    hi[j] = (_Float16)(float)h[0];  hi[j + 1] = (_Float16)(float)h[1];
    lo[j] = (_Float16)(float)l2[0]; lo[j + 1] = (_Float16)(float)l2[1];
  }
}

// R6 post-mortem: wave-independent structure = TLP collapse (8 waves/CU),
// ~33 us. Best remains the r0 block-cooperative form (~28 us kernel).
// This round, ONE variable vs r5 (r0 @ (256,4), 113.5 us): stage-3 W_f loads
// software-pipelined depth-1 across a flat 8-step loop, hiding one ~300 cy
// L2 round-trip per step. r3 tested this only bundled with a kernel-head
// sched_barrier(0) fence + depth-2 staging under the 85-VGPR cap; here it is
// isolated under the relaxed 128-VGPR cap (r5 proved (256,4) is perf-neutral).
__global__ __launch_bounds__(THREADS, 4)
void gnn_fused(const float* __restrict__ obs,
               const float* __restrict__ W_enc,
               const float* __restrict__ b_enc,
               const float* __restrict__ W_f,
               const float* __restrict__ b_f,
               const float* __restrict__ W_dec,
               const float* __restrict__ b_dec,
               float* __restrict__ out)
{
  // stride 132 floats: rows 528 B (16B-aligned), row-to-row bank shift of 4
  __shared__ __align__(16) float f_in[BT][132];   // stage-2 output [batch][128]
  __shared__ __align__(16) float hidn[BT][132];   // stage-3 output [batch][128]

  const int tid  = threadIdx.x;
  const int w    = tid >> 6;     // wave 0..3
  const int l    = tid & 63;     // lane
  const int m15  = l & 15;
  const int quad = l >> 4;
  const int b0   = blockIdx.x * BT;

  // ---- stage-1 B-fragments: W_enc[k][e] columns, hi/lo fp16, in regs (32 VGPRs)
  half8 we_hi[4], we_lo[4];
  float benc[4];
#pragma unroll
  for (int nt = 0; nt < 4; ++nt) {
    float f[8];
#pragma unroll
    for (int j = 0; j < 8; ++j)
      f[j] = W_enc[(size_t)(quad * 8 + j) * ENCD + nt * 16 + m15];
    split8(f, we_hi[nt], we_lo[nt]);
    benc[nt] = b_enc[nt * 16 + m15];
  }

  // ================= stage 1 (enc MFMA) + stage 2 (masked mean-pool) =========
  // wave handles batches [b0 + w*4, b0 + w*4 + 4)
  // lane's A-fragment = states[b][m15][quad*8 .. +8) : 32 contiguous bytes in HBM
  const float* bp = obs + (size_t)(b0 + w * 4) * (NS * SS) + m15 * SS + quad * 8;
  float4 c0 = ((const float4*)bp)[0];
  float4 c1 = ((const float4*)bp)[1];
#pragma unroll
  for (int i = 0; i < 4; ++i) {
    float4 n0, n1;
    if (i < 3) {  // prefetch next batch element
      const float* np = bp + (size_t)(i + 1) * (NS * SS);
      n0 = ((const float4*)np)[0];
      n1 = ((const float4*)np)[1];
    } else { n0 = c0; n1 = c1; }

    float f[8] = {c0.x, c0.y, c0.z, c0.w, c1.x, c1.y, c1.z, c1.w};

    // flags: lanes 0..15 hold states[b][n][0]; cumprod run length via ballot+ctz
    unsigned long long bal = __ballot((l < 16) && (f[0] == 1.0f));
    int run = __builtin_ctzll(~(bal >> 1));      // consecutive valid neighbors, 0..15
    float inv = 1.0f / fmaxf((float)run, 1.0f);

    half8 ahi, alo;
    split8(f, ahi, alo);

    const int bi = w * 4 + i;  // local batch row
#pragma unroll
    for (int nt = 0; nt < 4; ++nt) {
      f32x4 acc = {0.f, 0.f, 0.f, 0.f};
      acc = MFMA(ahi, we_hi[nt], acc);
      acc = MFMA(alo, we_hi[nt], acc);
      acc = MFMA(ahi, we_lo[nt], acc);
      // D layout: lane holds enc[n = quad*4 + r][e = nt*16 + m15]
      float s = 0.f, e0 = 0.f;
#pragma unroll
      for (int r = 0; r < 4; ++r) {
        int n = quad * 4 + r;
        float v = fmaxf(acc[r] + benc[nt], 0.f);
        if (n == 0) e0 = v;                    // agent row
        if (n >= 1 && n <= run) s += v;        // valid neighbor
      }
      s += __shfl_xor(s, 16, 64);              // reduce across quads
      s += __shfl_xor(s, 32, 64);
      if (quad == 0) {
        f_in[bi][nt * 16 + m15]      = e0;      // agent_enc
        f_in[bi][64 + nt * 16 + m15] = s * inv; // agg
      }
    }
    c0 = n0; c1 = n1;
  }
  __syncthreads();

  // ================= stage 3: hidden = relu(f_in @ W_f + b_f) ================
  // single 16-row M-tile; wave w covers N-tiles 2w, 2w+1. Flat s = tt*4+ks loop
  // with depth-1 W_f prefetch: step s+1's 8 loads issue before step s's
  // split8+MFMAs, so each ~300 cy L2 round-trip hides under compute.
  {
    half8 fa_hi[4], fa_lo[4];
#pragma unroll
    for (int ks = 0; ks < 4; ++ks) {
      const float4* p = (const float4*)&f_in[m15][ks * 32 + quad * 8];
      float4 a = p[0], b = p[1];
      float f[8] = {a.x, a.y, a.z, a.w, b.x, b.y, b.z, b.w};
      split8(f, fa_hi[ks], fa_lo[ks]);
    }
    const float bf0 = b_f[(w * 2) * 16 + m15];       // hoisted off the tail
    const float bf1 = b_f[(w * 2 + 1) * 16 + m15];

    float cur[8], nxt[8];
#pragma unroll
    for (int j = 0; j < 8; ++j)                      // s=0 fragment (tt=0,ks=0)
      cur[j] = W_f[(size_t)(quad * 8 + j) * HIDD + (w * 2) * 16 + m15];

    f32x4 acc = {0.f, 0.f, 0.f, 0.f};
#pragma unroll
    for (int s = 0; s < 8; ++s) {
      const int tt = s >> 2, ks = s & 3;
      if (s < 7) {                                   // prefetch step s+1
        const int nt2 = (s + 1) >> 2, nk = (s + 1) & 3;
        const int hn  = (w * 2 + nt2) * 16 + m15;
#pragma unroll
        for (int j = 0; j < 8; ++j)
          nxt[j] = W_f[(size_t)(nk * 32 + quad * 8 + j) * HIDD + hn];
      }
      half8 bhi, blo;
      split8(cur, bhi, blo);
      acc = MFMA(fa_hi[ks], bhi, acc);
      acc = MFMA(fa_lo[ks], bhi, acc);
      acc = MFMA(fa_hi[ks], blo, acc);
      if (ks == 3) {
        const int   hc  = (w * 2 + tt) * 16 + m15;
        const float bfv = tt ? bf1 : bf0;
#pragma unroll
        for (int r = 0; r < 4; ++r)                  // D: row = batch, col = hc
          hidn[quad * 4 + r][hc] = fmaxf(acc[r] + bfv, 0.f);
        acc = (f32x4){0.f, 0.f, 0.f, 0.f};
      }
#pragma unroll
      for (int j = 0; j < 8; ++j) cur[j] = nxt[j];   // rotate (SSA-renamed)
    }
  }
  __syncthreads();

  // ================= stage 4: logits = hidden @ W_dec + b_dec ================
  if (w == 0) {                                  // one 16-row M-tile (r0 form)
    half8 ga_hi[4], ga_lo[4];
#pragma unroll
    for (int ks = 0; ks < 4; ++ks) {
      const float4* p = (const float4*)&hidn[m15][ks * 32 + quad * 8];
      float4 a = p[0], b = p[1];
      float f[8] = {a.x, a.y, a.z, a.w, b.x, b.y, b.z, b.w};
      split8(f, ga_hi[ks], ga_lo[ks]);
    }
    f32x4 acc = {0.f, 0.f, 0.f, 0.f};
#pragma unroll
    for (int ks = 0; ks < 4; ++ks) {
      float f[8];
#pragma unroll
      for (int j = 0; j < 8; ++j) {
        int k = ks * 32 + quad * 8 + j;
        f[j] = (m15 < OUTD) ? W_dec[(size_t)k * OUTD + m15] : 0.f;  // pad N 8->16
      }
      half8 bhi, blo;
      split8(f, bhi, blo);
      acc = MFMA(ga_hi[ks], bhi, acc);
      acc = MFMA(ga_lo[ks], bhi, acc);
      acc = MFMA(ga_hi[ks], blo, acc);
    }
    if (m15 < OUTD) {
      const float bd = b_dec[m15];
#pragma unroll
      for (int r = 0; r < 4; ++r) {
        const int m = quad * 4 + r;
        out[(size_t)(b0 + m) * OUTD + m15] = acc[r] + bd;
      }
    }
  }
}

extern "C" void kernel_launch(void* const* d_in, const int* in_sizes, int n_in,
                              void* d_out, int out_size, void* d_ws, size_t ws_size,
                              hipStream_t stream) {
  (void)in_sizes; (void)n_in; (void)d_ws; (void)ws_size; (void)out_size;
  const float* obs   = (const float*)d_in[0];
  const float* W_enc = (const float*)d_in[1];
  const float* b_enc = (const float*)d_in[2];
  const float* W_f   = (const float*)d_in[3];
  const float* b_f   = (const float*)d_in[4];
  const float* W_dec = (const float*)d_in[5];
  const float* b_dec = (const float*)d_in[6];
  float* out = (float*)d_out;

  dim3 grid(NB / BT);      // 2048 blocks
  dim3 block(THREADS);     // 256 threads = 4 waves
  gnn_fused<<<grid, block, 0, stream>>>(obs, W_enc, b_enc, W_f, b_f, W_dec, b_dec, out);
}